// Round 1
// 11245.391 us; speedup vs baseline: 1.9396x; 1.9396x over previous
//
#include <hip/hip_runtime.h>

#define B_ 32
#define S_ 512
#define H_ 1024
#define L_ 3
#define BH (B_*H_)     // 32768
#define NBLK 512
#define PLANE 32768    // u16 elems in one A-frag-packed 32x1024 activation plane

typedef __attribute__((ext_vector_type(8))) short short8;
typedef __attribute__((ext_vector_type(4))) float f4;

__device__ __forceinline__ unsigned short f2bf(float f){
  unsigned int u = __float_as_uint(f);
  u += 0x7fffu + ((u >> 16) & 1u);   // RNE
  return (unsigned short)(u >> 16);
}
__device__ __forceinline__ float sigmoidf_(float x){
  return 1.0f / (1.0f + __expf(-x));
}
// offset (u16) of element (batch-row b, feature n) inside an A-frag-packed plane
// plane layout: [mh(2)][kb(32)][lane(64)][j(8)], lane = quad*16 + row
__device__ __forceinline__ int afrag_off(int b, int n){
  int mh = b >> 4, row = b & 15;
  int kb = n >> 5, quad = (n >> 3) & 3, j = n & 7;
  return (((mh * 32 + kb) * 64) + quad * 16 + row) * 8 + j;
}

// -------- device-coherent (agent scope, sc1: IC is coherence point) helpers --
// Writes go through L2 to Infinity Cache; reads bypass stale L1/L2. This makes
// cross-block data coherent WITHOUT any buffer_wbl2/buffer_inv cache walks.
__device__ __forceinline__ short8 ld16dc(const unsigned short* p){
  const unsigned long long* q = (const unsigned long long*)p;
  unsigned long long lo = __hip_atomic_load(q,     __ATOMIC_RELAXED, __HIP_MEMORY_SCOPE_AGENT);
  unsigned long long hi = __hip_atomic_load(q + 1, __ATOMIC_RELAXED, __HIP_MEMORY_SCOPE_AGENT);
  short8 v;
  ((unsigned long long*)&v)[0] = lo;
  ((unsigned long long*)&v)[1] = hi;
  return v;
}
__device__ __forceinline__ float ldf_dc(const float* p){
  return __hip_atomic_load(p, __ATOMIC_RELAXED, __HIP_MEMORY_SCOPE_AGENT);
}
__device__ __forceinline__ void stf_dc(float* p, float v){
  __hip_atomic_store(p, v, __ATOMIC_RELAXED, __HIP_MEMORY_SCOPE_AGENT);
}
__device__ __forceinline__ void stu16_dc(unsigned short* p, unsigned short v){
  __hip_atomic_store(p, v, __ATOMIC_RELAXED, __HIP_MEMORY_SCOPE_AGENT);
}

// ---------------- prep: pack weights in MFMA-fragment order -----------------
__global__ void prep_WA_packed(const float* __restrict__ Wx, const float* __restrict__ Wz,
                               const float* __restrict__ Wr, const float* __restrict__ Wh,
                               unsigned short* __restrict__ WAp){
  int idx = blockIdx.x * blockDim.x + threadIdx.x;  // 384*64*64 exact
  int lane = idx & 63;
  int kb = (idx >> 6) & 63;
  int tile = idx >> 12;
  int g = tile >> 7, jt = tile & 127;
  int quad = lane >> 4, l15 = lane & 15;
  int n = jt * 16 + l15;
  int k0 = kb * 32 + quad * 8;
  int col = n & 1023;
  const float* W = (k0 < 1024) ? ((n < 1024) ? Wx : Wr) : ((n < 1024) ? Wz : Wh);
  const float* src = W + ((size_t)g * 1024 + (k0 & 1023)) * 1024 + col;
  short8 v;
  #pragma unroll
  for (int j = 0; j < 8; ++j) v[j] = (short)f2bf(src[(size_t)j * 1024]);
  *(short8*)(WAp + (size_t)idx * 8) = v;
}

__global__ void prep_WB_packed(const float* __restrict__ Wg, const float* __restrict__ Whg,
                               unsigned short* __restrict__ WBp){
  int idx = blockIdx.x * blockDim.x + threadIdx.x;  // 192*64*64 exact
  int lane = idx & 63;
  int kb = (idx >> 6) & 63;
  int tile = idx >> 12;
  int g = tile >> 6, jt = tile & 63;
  int quad = lane >> 4, l15 = lane & 15;
  int n = jt * 16 + l15;
  int k0 = kb * 32 + quad * 8;
  const float* W = (k0 < 1024) ? Wg : Whg;
  const float* src = W + ((size_t)g * 1024 + (k0 & 1023)) * 1024 + n;
  short8 v;
  #pragma unroll
  for (int j = 0; j < 8; ++j) v[j] = (short)f2bf(src[(size_t)j * 1024]);
  *(short8*)(WBp + (size_t)idx * 8) = v;
}

__global__ void prep_Wout_packed(const float* __restrict__ Wout,
                                 unsigned short* __restrict__ WoutP){
  int idx = blockIdx.x * blockDim.x + threadIdx.x;  // 64*32*64 exact
  int lane = idx & 63;
  int kb = (idx >> 6) & 31;
  int tile = idx >> 11;
  int quad = lane >> 4, l15 = lane & 15;
  int n = tile * 16 + l15;
  int k0 = kb * 32 + quad * 8;
  const float* src = Wout + (size_t)k0 * 1024 + n;
  short8 v;
  #pragma unroll
  for (int j = 0; j < 8; ++j) v[j] = (short)f2bf(src[(size_t)j * 1024]);
  *(short8*)(WoutP + (size_t)idx * 8) = v;
}

__global__ void prep_X_packed(const float* __restrict__ x, unsigned short* __restrict__ Xp){
  size_t idx = (size_t)blockIdx.x * blockDim.x + threadIdx.x;  // 512*32768 exact
  int j = (int)(idx & 7);
  int lane = (int)((idx >> 3) & 63);
  int kb = (int)((idx >> 9) & 31);
  int mh = (int)((idx >> 14) & 1);
  int t = (int)(idx >> 15);
  int b = mh * 16 + (lane & 15);
  int i = kb * 32 + (lane >> 4) * 8 + j;
  Xp[idx] = f2bf(x[((size_t)b * S_ + t) * 1024 + i]);
}

__global__ void prep_H0_kernel(const float* __restrict__ h0,
                               unsigned short* __restrict__ HTb, float* __restrict__ HTf,
                               unsigned short* __restrict__ hfinp){
  int idx = blockIdx.x * blockDim.x + threadIdx.x;  // 3*32*1024 exact
  int h = idx & 1023;
  int b = (idx >> 10) & 31;
  int v = idx >> 15;
  float val = h0[((size_t)b * L_ + v) * 1024 + h];
  HTb[idx] = f2bf(val);
  HTf[idx] = val;                              // ring slot v&7 == v for v<3
  hfinp[(size_t)v * PLANE + afrag_off(b, h)] = f2bf(val);
}

// ---------------- cheap monotonic tree barrier (pure counters) --------------
// bar layout (uints): sub[x] at x*16 (x=0..7), top at 128, gen at 144.
// No cache maintenance: all cross-block data moves via agent-scope (sc1)
// loads/stores that are coherent at the Infinity Cache. __syncthreads drains
// vmcnt(0), so all write-through stores are IC-visible before arrival.
__device__ __forceinline__ void tree_barrier(unsigned* bar, unsigned target){
  __syncthreads();   // drains vmcnt for all waves of this block
  if (threadIdx.x == 0){
    unsigned* sub = bar + (blockIdx.x & 7) * 16;
    unsigned* top = bar + 128;
    unsigned* gen = bar + 144;
    unsigned old = __hip_atomic_fetch_add(sub, 1u, __ATOMIC_RELAXED, __HIP_MEMORY_SCOPE_AGENT);
    if (old == target * (NBLK / 8) - 1u){
      unsigned t2 = __hip_atomic_fetch_add(top, 1u, __ATOMIC_RELAXED, __HIP_MEMORY_SCOPE_AGENT);
      if (t2 == target * 8u - 1u)
        __hip_atomic_store(gen, target, __ATOMIC_RELAXED, __HIP_MEMORY_SCOPE_AGENT);
    }
    while (__hip_atomic_load(gen, __ATOMIC_RELAXED, __HIP_MEMORY_SCOPE_AGENT) < target)
      __builtin_amdgcn_s_sleep(1);
  }
  __syncthreads();
}

// 64-step K loop: first 32 kb from inp (cached if read-only Xp, else DC),
// second 32 kb from st/rp (always DC). Weights from LDS or cached global.
template<bool DCI>
__device__ __forceinline__ f4 gemm64(const unsigned short* __restrict__ inp,
                                     const unsigned short* __restrict__ st,
                                     const unsigned short* w,
                                     int mh, int lane){
  f4 acc = {0.f, 0.f, 0.f, 0.f};
  #pragma unroll 8
  for (int kb = 0; kb < 32; ++kb){
    short8 a = DCI ? ld16dc(inp + (size_t)((mh * 32 + kb) * 64 + lane) * 8)
                   : *(const short8*)(inp + (size_t)((mh * 32 + kb) * 64 + lane) * 8);
    short8 bv = *(const short8*)(w + (size_t)(kb * 64 + lane) * 8);
    acc = __builtin_amdgcn_mfma_f32_16x16x32_bf16(a, bv, acc, 0, 0, 0);
  }
  #pragma unroll 8
  for (int kb = 32; kb < 64; ++kb){
    short8 a = ld16dc(st + (size_t)((mh * 32 + kb - 32) * 64 + lane) * 8);
    short8 bv = *(const short8*)(w + (size_t)(kb * 64 + lane) * 8);
    acc = __builtin_amdgcn_mfma_f32_16x16x32_bf16(a, bv, acc, 0, 0, 0);
  }
  return acc;
}

// ---------------- persistent recurrence: LDS-resident weights ---------------
// 512 blocks x 128 threads (2 waves: wave = mh). 64 KB LDS/block = 2 blocks/CU.
// Blocks 0..383: own A-tile (g=blk>>7, jt=blk&127) in LDS.
// Blocks 384..511: own B-tile (g=(blk-384)>>6, jt=(blk-384)&63) in LDS.
// Blocks 320..383: additionally run B-tiles of layer 2 (jt=blk-320) streamed from global.
__global__ __launch_bounds__(128) void gru_persist(
    const unsigned short* __restrict__ WAp, const unsigned short* __restrict__ WBp,
    const unsigned short* __restrict__ Xp,
    unsigned short* __restrict__ hL0p, unsigned short* __restrict__ hL1p,
    unsigned short* __restrict__ hfinp,
    unsigned short* __restrict__ HTb, float* __restrict__ HTf,
    float* __restrict__ zbuf, unsigned short* __restrict__ rsp,
    const float* __restrict__ bz, const float* __restrict__ br,
    const float* __restrict__ bg, unsigned* bar)
{
  __shared__ unsigned short ldsw[32768];   // 64 KB weight tile
  const int blk = blockIdx.x;
  const int lane = threadIdx.x & 63;
  const int mh = threadIdx.x >> 6;
  const int quad = lane >> 4, l15 = lane & 15;

  // bootstrap: copy this block's weight tile into LDS (coalesced 16B/lane)
  {
    const unsigned short* src = (blk < 384) ? WAp + (size_t)blk * 32768
                                            : WBp + (size_t)(blk - 384) * 32768;
    for (int i = threadIdx.x; i < 4096; i += 128)
      *(short8*)(ldsw + (size_t)i * 8) = *(const short8*)(src + (size_t)i * 8);
  }
  __syncthreads();

  const int gA = blk >> 7, jtA = blk & 127;
  int gB = -1, jtB = 0;
  const unsigned short* wBg = nullptr;     // non-null => stream B weights from global
  if (blk >= 384){ gB = (blk - 384) >> 6; jtB = (blk - 384) & 63; }
  else if (blk >= 320){ gB = 2; jtB = blk - 320; wBg = WBp + (size_t)(128 + (blk - 320)) * 32768; }

  // hoisted per-thread biases (fixed columns per block)
  float biasA = 0.f, biasB = 0.f;
  if (blk < 384){
    int n2 = jtA * 16 + l15;
    biasA = (jtA < 64) ? bz[gA * H_ + n2] : br[gA * H_ + n2 - 1024];
  }
  if (gB >= 0) biasB = bg[gB * H_ + jtB * 16 + l15];

  unsigned tgt = 1;
  for (int s = -4; s <= 2 * S_ - 1; ++s){
    int u = ((s & 1) ? (s - 1) : s) / 2;   // exact
    int v = u + 2;                          // state index this slot
    if (!(s & 1)){
      // ---------------- A phase ----------------
      if (blk < 384){
        int t = u + 2 - gA;
        if (t >= 0 && t < S_){
          int tm = t & 3;
          const unsigned short* inp = (gA == 0) ? Xp + (size_t)t * PLANE
                                    : (gA == 1) ? hL0p + (size_t)tm * PLANE
                                                : hL1p + (size_t)tm * PLANE;
          const unsigned short* st = hfinp + (size_t)(v & 7) * PLANE;
          f4 acc = (gA == 0) ? gemm64<false>(inp, st, ldsw, mh, lane)
                             : gemm64<true >(inp, st, ldsw, mh, lane);
          int n2 = jtA * 16 + l15;
          const float* sf = HTf + (size_t)(v & 7) * BH;
          if (jtA < 64){
            float* zb = zbuf + (size_t)(gA * 4 + tm) * BH;
            #pragma unroll
            for (int r = 0; r < 4; ++r){
              int b = mh * 16 + quad * 4 + r;
              stf_dc(zb + b * H_ + n2, sigmoidf_(acc[r] + biasA));
            }
          } else {
            int n = n2 - 1024;
            unsigned short* rp = rsp + (size_t)(gA * 4 + tm) * PLANE;
            #pragma unroll
            for (int r = 0; r < 4; ++r){
              int b = mh * 16 + quad * 4 + r;
              float sv = ldf_dc(sf + b * H_ + n);
              stu16_dc(rp + afrag_off(b, n), f2bf(sigmoidf_(acc[r] + biasA) * sv));
            }
          }
        }
      }
    } else {
      // ---------------- B phase ----------------
      if (gB >= 0){
        int t = u + 2 - gB;
        if (t >= 0 && t < S_){
          int tm = t & 3;
          const unsigned short* inp = (gB == 0) ? Xp + (size_t)t * PLANE
                                    : (gB == 1) ? hL0p + (size_t)tm * PLANE
                                                : hL1p + (size_t)tm * PLANE;
          const unsigned short* rp = rsp + (size_t)(gB * 4 + tm) * PLANE;
          f4 acc;
          if (!wBg)
            acc = (gB == 0) ? gemm64<false>(inp, rp, ldsw, mh, lane)
                            : gemm64<true >(inp, rp, ldsw, mh, lane);
          else
            acc = gemm64<true>(inp, rp, wBg, mh, lane);
          int n = jtB * 16 + l15;
          const float* sf = HTf + (size_t)(v & 7) * BH;
          const float* zb = zbuf + (size_t)(gB * 4 + tm) * BH;
          #pragma unroll
          for (int r = 0; r < 4; ++r){
            int b = mh * 16 + quad * 4 + r;
            float gg = tanhf(acc[r] + biasB);
            float z = ldf_dc(zb + b * H_ + n);
            float sv = ldf_dc(sf + b * H_ + n);
            float h = z * sv + (1.f - z) * gg;
            unsigned short hb = f2bf(h);
            if (gB == 2){
              stf_dc(HTf + (size_t)((t + 3) & 7) * BH + b * H_ + n, h);
              HTb[(size_t)(t + 3) * BH + b * H_ + n] = hb;   // plain: read post-kernel only
              stu16_dc(hfinp + (size_t)((t + 3) & 7) * PLANE + afrag_off(b, n), hb);
            } else if (gB == 0){
              stu16_dc(hL0p + (size_t)tm * PLANE + afrag_off(b, n), hb);
            } else {
              stu16_dc(hL1p + (size_t)tm * PLANE + afrag_off(b, n), hb);
            }
          }
        }
      }
    }
    tree_barrier(bar, tgt++);
  }
}

// ---------------- epilogue: Y = HT @ Wout + bout ----------------------------
__global__ __launch_bounds__(256) void out_proj_kernel(
    const unsigned short* __restrict__ HTb, const unsigned short* __restrict__ WoutP,
    const float* __restrict__ bout, float* __restrict__ Y){
  int tstep = blockIdx.x >> 2;
  int nblk  = blockIdx.x & 3;
  int wave = threadIdx.x >> 6, lane = threadIdx.x & 63;
  int quad = lane >> 4, l15 = lane & 15;
  const unsigned short* A = HTb + (size_t)(tstep + 3) * BH;
  f4 acc[2][4] = {};
  for (int kk = 0; kk < 32; ++kk){
    int k0 = kk * 32 + quad * 8;
    short8 a0 = *(const short8*)(A + l15 * H_ + k0);
    short8 a1 = *(const short8*)(A + (l15 + 16) * H_ + k0);
    #pragma unroll
    for (int nt = 0; nt < 4; ++nt){
      int tile = nblk * 16 + wave * 4 + nt;
      short8 bv = ((const short8*)WoutP)[((size_t)tile * 32 + kk) * 64 + lane];
      acc[0][nt] = __builtin_amdgcn_mfma_f32_16x16x32_bf16(a0, bv, acc[0][nt], 0, 0, 0);
      acc[1][nt] = __builtin_amdgcn_mfma_f32_16x16x32_bf16(a1, bv, acc[1][nt], 0, 0, 0);
    }
  }
  #pragma unroll
  for (int mt = 0; mt < 2; ++mt)
    #pragma unroll
    for (int nt = 0; nt < 4; ++nt)
      #pragma unroll
      for (int r = 0; r < 4; ++r){
        int b = mt * 16 + quad * 4 + r;
        int n = nblk * 256 + wave * 64 + nt * 16 + l15;
        Y[(size_t)b * (S_ * 1024) + (size_t)tstep * 1024 + n] = acc[mt][nt][r] + bout[n];
      }
}

__global__ void copy_hidden_kernel(const float* __restrict__ HTf, float* __restrict__ out2){
  int idx = blockIdx.x * blockDim.x + threadIdx.x;  // 3*32*1024 exact
  int h = idx & 1023;
  int b = (idx >> 10) & 31;
  int v = idx >> 15;
  out2[((size_t)b * L_ + v) * 1024 + h] = HTf[(size_t)((S_ + v) & 7) * BH + b * H_ + h];
}

// ---------------------------------------------------------------------------
extern "C" void kernel_launch(void* const* d_in, const int* in_sizes, int n_in,
                              void* d_out, int out_size, void* d_ws, size_t ws_size,
                              hipStream_t stream){
  (void)in_sizes; (void)n_in; (void)out_size;
  const float* x    = (const float*)d_in[0];
  const float* h0   = (const float*)d_in[1];
  const float* Wx   = (const float*)d_in[2];
  const float* Wz   = (const float*)d_in[3];
  const float* bz   = (const float*)d_in[4];
  const float* Wr   = (const float*)d_in[5];
  const float* Wh   = (const float*)d_in[6];
  const float* br   = (const float*)d_in[7];
  const float* Wg   = (const float*)d_in[8];
  const float* Whg  = (const float*)d_in[9];
  const float* bg   = (const float*)d_in[10];
  const float* Wout = (const float*)d_in[11];
  const float* bout = (const float*)d_in[12];
  float* out = (float*)d_out;

  char* p = (char*)d_ws;
  unsigned short* WAp   = (unsigned short*)p; p += (size_t)384 * 32768 * 2;
  unsigned short* WBp   = (unsigned short*)p; p += (size_t)192 * 32768 * 2;
  unsigned short* WoutP = (unsigned short*)p; p += (size_t)64 * 32 * 64 * 8 * 2;
  unsigned short* Xp    = (unsigned short*)p; p += (size_t)S_ * PLANE * 2;
  unsigned short* HTb   = (unsigned short*)p; p += (size_t)(S_ + 3) * BH * 2;
  float*          HTf   = (float*)p;          p += (size_t)8 * BH * 4;
  unsigned short* hfinp = (unsigned short*)p; p += (size_t)8 * PLANE * 2;
  unsigned short* hL0p  = (unsigned short*)p; p += (size_t)4 * PLANE * 2;
  unsigned short* hL1p  = (unsigned short*)p; p += (size_t)4 * PLANE * 2;
  unsigned short* rsp   = (unsigned short*)p; p += (size_t)12 * PLANE * 2;
  float*          zbuf  = (float*)p;          p += (size_t)12 * BH * 4;
  unsigned*       bar   = (unsigned*)p;       p += 4096;
  if ((size_t)(p - (char*)d_ws) > ws_size) return;

  hipMemsetAsync(bar, 0, 4096, stream);
  prep_WA_packed  <<<6144, 256, 0, stream>>>(Wx, Wz, Wr, Wh, WAp);
  prep_WB_packed  <<<3072, 256, 0, stream>>>(Wg, Whg, WBp);
  prep_Wout_packed<<< 512, 256, 0, stream>>>(Wout, WoutP);
  prep_X_packed   <<<65536, 256, 0, stream>>>(x, Xp);
  prep_H0_kernel  <<<  384, 256, 0, stream>>>(h0, HTb, HTf, hfinp);

  gru_persist<<<NBLK, 128, 0, stream>>>(WAp, WBp, Xp, hL0p, hL1p, hfinp,
                                        HTb, HTf, zbuf, rsp, bz, br, bg, bar);

  out_proj_kernel   <<<2048, 256, 0, stream>>>(HTb, WoutP, bout, out);
  copy_hidden_kernel<<< 384, 256, 0, stream>>>(HTf, out + (size_t)B_ * S_ * 1024);
}